// Round 8
// baseline (39.262 us; speedup 1.0000x reference)
//
#include <hip/hip_runtime.h>

#define N1 4096
#define N2 8192
#define FDIM 256
#define HDIM 128
#define OUTD 128

typedef float fx4 __attribute__((ext_vector_type(4)));

// mish(x) = x * tanh(softplus(x)) = x * (w2-1)/(w2+1), w = 1+e^x
//         = x - 2x/(w2+1)   [8 VALU ops, 2 quarter-rate]
__device__ __forceinline__ float mishf(float x) {
    float e = __expf(fminf(x, 30.0f));
    float w = 1.0f + e;
    float q = __builtin_fmaf(w, w, 1.0f);      // w^2 + 1
    float r = __builtin_amdgcn_rcpf(q);
    return __builtin_fmaf(x, -2.0f * r, x);    // x - 2x/q
}

// 512 waves, one per output element: v[c] = dot(w[c,:], a-slice).
// Spread across 128 blocks so the 256 KB of w reads use many CUs' HBM share.
__global__ void compute_v_kernel(const float* __restrict__ w_m,
                                 const float* __restrict__ w_d,
                                 const float* __restrict__ a,
                                 float* __restrict__ v /* 512 floats: v_m | v_d */) {
    int wave = (blockIdx.x << 2) + (threadIdx.x >> 6);   // 0..511
    int lane = threadIdx.x & 63;
    const float* wr = (wave < 256) ? (w_m + wave * OUTD) : (w_d + (wave - 256) * OUTD);
    const float* av = (wave < 256) ? a : (a + 2 * OUTD);
    float2 wv = ((const float2*)wr)[lane];
    float2 aa = ((const float2*)av)[lane];
    float s = wv.x * aa.x + wv.y * aa.y;
    #pragma unroll
    for (int off = 32; off > 0; off >>= 1) s += __shfl_down(s, off, 64);
    if (lane == 0) v[wave] = s;
}

// One wave (64 lanes) per row. Lane l handles cols [4l, 4l+4) via float4.
// x[i] = sum_c (am0*m+am1*m1+am2*m2)[i,c]*v_m[c] + sum_h m_h[i,h]*a[128+h]
__global__ void compute_xy_kernel(const float* __restrict__ m,  const float* __restrict__ m1,
                                  const float* __restrict__ m2, const float* __restrict__ m_h,
                                  const float* __restrict__ d,  const float* __restrict__ d1,
                                  const float* __restrict__ d2, const float* __restrict__ d_h,
                                  const float* __restrict__ a_m, const float* __restrict__ a_d,
                                  const float* __restrict__ a,
                                  const float* __restrict__ v,
                                  float* __restrict__ xy /* x[0..N1) then y[N1..N1+N2) */) {
    int gtid = blockIdx.x * blockDim.x + threadIdx.x;
    int row  = gtid >> 6;                 // one wave per row
    int lane = threadIdx.x & 63;

    const float *pm, *pm1, *pm2, *ph, *pa, *pv;
    float c0, c1, c2;
    int r;
    if (row < N1) {
        r = row;
        pm = m; pm1 = m1; pm2 = m2; ph = m_h;
        pa = a + OUTD;                    // a1[128:256]
        pv = v;
        c0 = a_m[0]; c1 = a_m[1]; c2 = a_m[2];
    } else {
        r = row - N1;
        pm = d; pm1 = d1; pm2 = d2; ph = d_h;
        pa = a + 2 * OUTD + HDIM;         // a2[128:256] = a[384:512]
        pv = v + 256;
        c0 = a_d[0]; c1 = a_d[1]; c2 = a_d[2];
    }

    fx4 v0 = ((const fx4*)(pm  + (size_t)r * FDIM))[lane];
    fx4 v1 = ((const fx4*)(pm1 + (size_t)r * FDIM))[lane];
    fx4 v2 = ((const fx4*)(pm2 + (size_t)r * FDIM))[lane];
    fx4 vv = ((const fx4*)pv)[lane];

    float val = (c0 * v0.x + c1 * v1.x + c2 * v2.x) * vv.x
              + (c0 * v0.y + c1 * v1.y + c2 * v2.y) * vv.y
              + (c0 * v0.z + c1 * v1.z + c2 * v2.z) * vv.z
              + (c0 * v0.w + c1 * v1.w + c2 * v2.w) * vv.w;

    if (lane < 32) {                      // 128 H-cols = 32 lanes x float4
        fx4 hv = ((const fx4*)(ph + (size_t)r * HDIM))[lane];
        fx4 av = ((const fx4*)pa)[lane];
        val += hv.x * av.x + hv.y * av.y + hv.z * av.z + hv.w * av.w;
    }

    #pragma unroll
    for (int off = 32; off > 0; off >>= 1) val += __shfl_down(val, off, 64);
    if (lane == 0) xy[row] = val;
}

// s[i,j] = mish(x[i] + y[j]) — streaming-store, 16 stores per wave.
// Wave owns a 128-fx4 col window (2 fx4/lane, loaded once) x 8 rows:
// per row two back-to-back stores = 2 KB contiguous; block bursts 8 KB/row.
// 8192 waves = 2048 blocks. Loads amortized over a 4 KB store stream.
__global__ void mish_bcast_kernel(const float* __restrict__ x,
                                  const float* __restrict__ y,
                                  fx4* __restrict__ out) {
    const unsigned gtid = blockIdx.x * blockDim.x + threadIdx.x;
    const unsigned wid  = gtid >> 6;           // 0..8191
    const unsigned lane = threadIdx.x & 63;
    const unsigned cg   = wid & 15;            // col-group: 128 fx4 each
    const unsigned rg   = wid >> 4;            // row-group: 8 rows each (0..511)
    const unsigned c0   = (cg << 7) + lane;    // first fx4 col
    const fx4* y4 = (const fx4*)y;

    fx4 y0 = y4[c0];
    fx4 y1 = y4[c0 + 64];
    fx4 xa = ((const fx4*)(x + (rg << 3)))[0];
    fx4 xb = ((const fx4*)(x + (rg << 3)))[1];
    float xs[8] = {xa.x, xa.y, xa.z, xa.w, xb.x, xb.y, xb.z, xb.w};

    fx4* o = out + ((size_t)(rg << 3) << 11) + c0;   // row rg*8, 2048 fx4/row
    #pragma unroll
    for (int rr = 0; rr < 8; ++rr) {
        float xi = xs[rr];
        fx4 r0, r1;
        r0.x = mishf(xi + y0.x);
        r0.y = mishf(xi + y0.y);
        r0.z = mishf(xi + y0.z);
        r0.w = mishf(xi + y0.w);
        r1.x = mishf(xi + y1.x);
        r1.y = mishf(xi + y1.y);
        r1.z = mishf(xi + y1.z);
        r1.w = mishf(xi + y1.w);
        o[0]  = r0;
        o[64] = r1;
        o += 2048;
    }
}

extern "C" void kernel_launch(void* const* d_in, const int* in_sizes, int n_in,
                              void* d_out, int out_size, void* d_ws, size_t ws_size,
                              hipStream_t stream) {
    const float* m   = (const float*)d_in[0];
    const float* m1  = (const float*)d_in[1];
    const float* m2  = (const float*)d_in[2];
    const float* m_h = (const float*)d_in[3];
    const float* d   = (const float*)d_in[4];
    const float* d1  = (const float*)d_in[5];
    const float* d2  = (const float*)d_in[6];
    const float* d_h = (const float*)d_in[7];
    const float* w_m = (const float*)d_in[8];
    const float* w_d = (const float*)d_in[9];
    const float* a_m = (const float*)d_in[10];
    const float* a_d = (const float*)d_in[11];
    const float* a   = (const float*)d_in[12];

    float* wsf = (float*)d_ws;
    float* v  = wsf;          // 512 floats
    float* xy = wsf + 512;    // 4096 + 8192 floats

    compute_v_kernel<<<128, 256, 0, stream>>>(w_m, w_d, a, v);
    // one wave per row: (N1+N2) waves = 12288 -> 3072 blocks of 256 threads
    compute_xy_kernel<<<(N1 + N2) / 4, 256, 0, stream>>>(m, m1, m2, m_h, d, d1, d2, d_h,
                                                         a_m, a_d, a, v, xy);
    // 8192 waves: 512 row-groups (8 rows) x 16 col-groups (512 floats)
    mish_bcast_kernel<<<2048, 256, 0, stream>>>(xy, xy + N1, (fx4*)d_out);
}